// Round 1
// baseline (220.740 us; speedup 1.0000x reference)
//
#include <hip/hip_runtime.h>
#include <hip/hip_bf16.h>

// Problem constants
#define NB    4
#define NP    12          // P1 == P == 12
#define NN_   207
#define DM    128         // d_model
#define DHID  256
#define M_TOK 9936        // NB*NP*NN_
#define M_PAD 9984        // padded to 78*128
#define KSPLIT 8          // j-splits (j-chunk = 32)

typedef float        f32x4 __attribute__((ext_vector_type(4)));
typedef unsigned int u32x4 __attribute__((ext_vector_type(4)));

static __device__ __forceinline__ unsigned int pk_bf2(float a, float b) {
    __hip_bfloat16 ba = __float2bfloat16(a);
    __hip_bfloat16 bb = __float2bfloat16(b);
    unsigned short ua = *reinterpret_cast<unsigned short*>(&ba);
    unsigned short ub = *reinterpret_cast<unsigned short*>(&bb);
    return (unsigned int)ua | ((unsigned int)ub << 16);
}

// ---------------- kernel 1: W2 fp32 -> bf16 ----------------
__global__ __launch_bounds__(256) void k_cvt_w2(const float* __restrict__ w2,
                                                unsigned short* __restrict__ w2b) {
    int i = blockIdx.x * 256 + threadIdx.x;      // 524288 threads, 8 f32 each
    const f32x4* in = reinterpret_cast<const f32x4*>(w2);
    f32x4 v0 = in[2 * i], v1 = in[2 * i + 1];
    u32x4 o;
    o[0] = pk_bf2(v0[0], v0[1]);
    o[1] = pk_bf2(v0[2], v0[3]);
    o[2] = pk_bf2(v1[0], v1[1]);
    o[3] = pk_bf2(v1[2], v1[3]);
    reinterpret_cast<u32x4*>(w2b)[i] = o;
}

// ---------------- kernel 2: transpose inputs -> xT[128][M_PAD] (pad = 0) ----------------
__global__ __launch_bounds__(256) void k_transpose_x(const float* __restrict__ x,
                                                     float* __restrict__ xT) {
    __shared__ float tile[32][33];
    const int bm = blockIdx.x >> 2;   // 312 m-tiles
    const int bd = blockIdx.x & 3;    // 4 d-tiles
    const int m0 = bm * 32, d0 = bd * 32;
    const int t = threadIdx.x;
    #pragma unroll
    for (int i = 0; i < 4; ++i) {
        int e = i * 256 + t;
        int lm = e >> 5, ld = e & 31;
        int m = m0 + lm;
        tile[lm][ld] = (m < M_TOK) ? x[(size_t)m * DM + d0 + ld] : 0.0f;
    }
    __syncthreads();
    #pragma unroll
    for (int i = 0; i < 4; ++i) {
        int e = i * 256 + t;
        int ld = e >> 5, lm = e & 31;
        xT[(size_t)(d0 + ld) * M_PAD + m0 + lm] = tile[lm][ld];
    }
}

// ---------------- kernel 3: h = relu(W1 ct + b1); Qb = b2-resh . x ----------------
__global__ __launch_bounds__(256) void k_meta(const float* __restrict__ ct,
                                              const float* __restrict__ xin,
                                              const float* __restrict__ W1,
                                              const float* __restrict__ b1,
                                              const float* __restrict__ b2,
                                              float* __restrict__ hbuf,
                                              float* __restrict__ Qb) {
    __shared__ float cts[8][128];
    __shared__ float xs[8][128];
    const int t = threadIdx.x;
    const int m0 = blockIdx.x * 8;
    {   // stage 8 tokens of c_targets and inputs (256 f32x4 each)
        int tok = t >> 5, c4 = t & 31;
        *reinterpret_cast<f32x4*>(&cts[tok][c4 * 4]) =
            *reinterpret_cast<const f32x4*>(&ct[(size_t)(m0 + tok) * DM + c4 * 4]);
        *reinterpret_cast<f32x4*>(&xs[tok][c4 * 4]) =
            *reinterpret_cast<const f32x4*>(&xin[(size_t)(m0 + tok) * DM + c4 * 4]);
    }
    __syncthreads();
    {   // h: thread t owns output j = t for 8 tokens
        const int j = t;
        const f32x4* w1r = reinterpret_cast<const f32x4*>(&W1[(size_t)j * DM]);
        float acc[8] = {0, 0, 0, 0, 0, 0, 0, 0};
        for (int c = 0; c < 32; ++c) {
            f32x4 wv = w1r[c];
            #pragma unroll
            for (int tok = 0; tok < 8; ++tok) {
                f32x4 cv = *reinterpret_cast<const f32x4*>(&cts[tok][c * 4]);
                acc[tok] += wv[0] * cv[0] + wv[1] * cv[1] + wv[2] * cv[2] + wv[3] * cv[3];
            }
        }
        float bb = b1[j];
        #pragma unroll
        for (int tok = 0; tok < 8; ++tok)
            hbuf[(size_t)(m0 + tok) * DHID + j] = fmaxf(acc[tok] + bb, 0.0f);
    }
    {   // Qb: thread owns o = t&127 for 4 tokens
        const int o = t & 127;
        const int tg = (t >> 7) * 4;
        const f32x4* b2r = reinterpret_cast<const f32x4*>(&b2[(size_t)o * DM]);
        float acc[4] = {0, 0, 0, 0};
        for (int c = 0; c < 32; ++c) {
            f32x4 wv = b2r[c];
            #pragma unroll
            for (int tt = 0; tt < 4; ++tt) {
                f32x4 xv = *reinterpret_cast<const f32x4*>(&xs[tg + tt][c * 4]);
                acc[tt] += wv[0] * xv[0] + wv[1] * xv[1] + wv[2] * xv[2] + wv[3] * xv[3];
            }
        }
        #pragma unroll
        for (int tt = 0; tt < 4; ++tt)
            Qb[(size_t)(m0 + tg + tt) * DM + o] = acc[tt];
    }
}

// ---------------- kernel 4: the big bilinear GEMM (bf16 MFMA) ----------------
// Q[m, o] = sum_{d,j} bf16(x[m,d]*h[m,j]) * bf16(W2[o*128+d, j])
// Grid: 78 m-blocks * 8 j-splits. kid = blockIdx&7 -> same XCD caches one 1MB W2 slice.
__global__ __launch_bounds__(256, 3) void k_gemm(const unsigned short* __restrict__ W2b,
                                                 const float* __restrict__ hbuf,
                                                 const float* __restrict__ xT,
                                                 float* __restrict__ Qp) {
    __shared__ unsigned short As[128 * 40];   // 128 rows x 32 k (pad 40)
    __shared__ unsigned short Bs[128 * 40];
    const int t = threadIdx.x;
    const int kid = blockIdx.x & 7;
    const int mb = blockIdx.x >> 3;
    const int m0 = mb * 128;
    const int j0 = kid * 32;
    const int w = t >> 6;        // wave 0..3
    const int l = t & 63;
    const int obase = w * 32;

    // staging assignment: rows ro2 and ro2+64, k-chunk c2*8
    const int ro2 = t >> 2;      // 0..63
    const int c2 = t & 3;

    // h fragment in registers: reused for all 128 d-steps
    f32x4 h0a = *reinterpret_cast<const f32x4*>(&hbuf[(size_t)(m0 + ro2) * DHID + j0 + c2 * 8]);
    f32x4 h0b = *reinterpret_cast<const f32x4*>(&hbuf[(size_t)(m0 + ro2) * DHID + j0 + c2 * 8 + 4]);
    f32x4 h1a = *reinterpret_cast<const f32x4*>(&hbuf[(size_t)(m0 + 64 + ro2) * DHID + j0 + c2 * 8]);
    f32x4 h1b = *reinterpret_cast<const f32x4*>(&hbuf[(size_t)(m0 + 64 + ro2) * DHID + j0 + c2 * 8 + 4]);

    f32x4 acc[8][2];
    #pragma unroll
    for (int mt = 0; mt < 8; ++mt) {
        acc[mt][0] = (f32x4)(0.0f);
        acc[mt][1] = (f32x4)(0.0f);
    }

    const unsigned short* Bsrc = W2b + (size_t)j0 + c2 * 8;
    // prefetch d = 0
    u32x4 bv0 = *reinterpret_cast<const u32x4*>(Bsrc + (size_t)ro2 * 32768);
    u32x4 bv1 = *reinterpret_cast<const u32x4*>(Bsrc + (size_t)(64 + ro2) * 32768);
    float xv0 = xT[m0 + ro2];
    float xv1 = xT[m0 + 64 + ro2];

    const int kk = (l >> 4) * 8;
    const int lr = l & 15;

    for (int d = 0; d < 128; ++d) {
        __syncthreads();   // previous MFMA phase done reading LDS
        {
            u32x4 av;
            av[0] = pk_bf2(xv0 * h0a[0], xv0 * h0a[1]);
            av[1] = pk_bf2(xv0 * h0a[2], xv0 * h0a[3]);
            av[2] = pk_bf2(xv0 * h0b[0], xv0 * h0b[1]);
            av[3] = pk_bf2(xv0 * h0b[2], xv0 * h0b[3]);
            *reinterpret_cast<u32x4*>(&As[ro2 * 40 + c2 * 8]) = av;
            av[0] = pk_bf2(xv1 * h1a[0], xv1 * h1a[1]);
            av[1] = pk_bf2(xv1 * h1a[2], xv1 * h1a[3]);
            av[2] = pk_bf2(xv1 * h1b[0], xv1 * h1b[1]);
            av[3] = pk_bf2(xv1 * h1b[2], xv1 * h1b[3]);
            *reinterpret_cast<u32x4*>(&As[(64 + ro2) * 40 + c2 * 8]) = av;
            *reinterpret_cast<u32x4*>(&Bs[ro2 * 40 + c2 * 8]) = bv0;
            *reinterpret_cast<u32x4*>(&Bs[(64 + ro2) * 40 + c2 * 8]) = bv1;
        }
        if (d < 127) {     // prefetch next d under the MFMA phase (uniform branch)
            bv0 = *reinterpret_cast<const u32x4*>(Bsrc + (size_t)ro2 * 32768 + (d + 1) * 256);
            bv1 = *reinterpret_cast<const u32x4*>(Bsrc + (size_t)(64 + ro2) * 32768 + (d + 1) * 256);
            xv0 = xT[(size_t)(d + 1) * M_PAD + m0 + ro2];
            xv1 = xT[(size_t)(d + 1) * M_PAD + m0 + 64 + ro2];
        }
        __syncthreads();   // tile staged
        u32x4 bfr0 = *reinterpret_cast<const u32x4*>(&Bs[(obase + lr) * 40 + kk]);
        u32x4 bfr1 = *reinterpret_cast<const u32x4*>(&Bs[(obase + 16 + lr) * 40 + kk]);
        #pragma unroll
        for (int mt = 0; mt < 8; ++mt) {
            u32x4 afr = *reinterpret_cast<const u32x4*>(&As[(mt * 16 + lr) * 40 + kk]);
            asm("v_mfma_f32_16x16x32_bf16 %0, %1, %2, %0" : "+v"(acc[mt][0]) : "v"(afr), "v"(bfr0));
            asm("v_mfma_f32_16x16x32_bf16 %0, %1, %2, %0" : "+v"(acc[mt][1]) : "v"(afr), "v"(bfr1));
        }
    }

    // epilogue: D layout col = lane&15, row = (lane>>4)*4 + reg
    float* outp = Qp + (size_t)kid * M_PAD * DM;
    #pragma unroll
    for (int mt = 0; mt < 8; ++mt)
        #pragma unroll
        for (int ot = 0; ot < 2; ++ot)
            #pragma unroll
            for (int r = 0; r < 4; ++r) {
                int m = m0 + mt * 16 + (l >> 4) * 4 + r;
                int o = obase + ot * 16 + lr;
                outp[(size_t)m * DM + o] = acc[mt][ot][r];
            }
}

// ---------------- kernel 5: attention + W_out + residual + layernorm ----------------
__global__ __launch_bounds__(256) void k_attn(const float* __restrict__ Qp,
                                              const float* __restrict__ Qb,
                                              const float* __restrict__ Kenc,
                                              const float* __restrict__ Venc,
                                              const float* __restrict__ xin,
                                              const float* __restrict__ Wout,
                                              const float* __restrict__ gamma,
                                              const float* __restrict__ beta,
                                              float* __restrict__ out) {
    __shared__ float Qs[12][132];
    __shared__ float Ks[12][132];
    __shared__ float Vs[12][132];
    __shared__ float Ss[12][12][8];
    __shared__ float Os[12][132];
    __shared__ float Ws[64][132];
    const int t = threadIdx.x;
    const int b = blockIdx.x / NN_;
    const int n = blockIdx.x % NN_;

    // stage Q (sum of 8 partials + bias term), K, V
    for (int e = t; e < 384; e += 256) {
        int row = e >> 5, c4 = e & 31;
        size_t mrow = (size_t)(b * NP + row) * NN_ + n;
        f32x4 q = *reinterpret_cast<const f32x4*>(&Qb[mrow * DM + c4 * 4]);
        #pragma unroll
        for (int k = 0; k < KSPLIT; ++k)
            q += *reinterpret_cast<const f32x4*>(&Qp[((size_t)k * M_PAD + mrow) * DM + c4 * 4]);
        *reinterpret_cast<f32x4*>(&Qs[row][c4 * 4]) = q;
        *reinterpret_cast<f32x4*>(&Ks[row][c4 * 4]) =
            *reinterpret_cast<const f32x4*>(&Kenc[mrow * DM + c4 * 4]);
        *reinterpret_cast<f32x4*>(&Vs[row][c4 * 4]) =
            *reinterpret_cast<const f32x4*>(&Venc[mrow * DM + c4 * 4]);
    }
    __syncthreads();
    // scores
    if (t < 144) {
        int q = t / 12, p = t % 12;
        #pragma unroll
        for (int hh = 0; hh < 8; ++hh) {
            const f32x4* qv = reinterpret_cast<const f32x4*>(&Qs[q][hh * 16]);
            const f32x4* kv = reinterpret_cast<const f32x4*>(&Ks[p][hh * 16]);
            float s = 0.0f;
            #pragma unroll
            for (int c = 0; c < 4; ++c) {
                f32x4 a = qv[c], bb = kv[c];
                s += a[0] * bb[0] + a[1] * bb[1] + a[2] * bb[2] + a[3] * bb[3];
            }
            Ss[q][p][hh] = s * 0.25f;   // 1/sqrt(16)
        }
    }
    __syncthreads();
    // softmax over p
    if (t < 96) {
        int q = t >> 3, hh = t & 7;
        float mx = -1e30f;
        #pragma unroll
        for (int p = 0; p < 12; ++p) mx = fmaxf(mx, Ss[q][p][hh]);
        float ev[12]; float sum = 0.0f;
        #pragma unroll
        for (int p = 0; p < 12; ++p) { ev[p] = __expf(Ss[q][p][hh] - mx); sum += ev[p]; }
        float inv = 1.0f / sum;
        #pragma unroll
        for (int p = 0; p < 12; ++p) Ss[q][p][hh] = ev[p] * inv;
    }
    __syncthreads();
    // PV
    #pragma unroll
    for (int i = 0; i < 6; ++i) {
        int e = i * 256 + t;
        int q = e >> 7, hk = e & 127, hh = hk >> 4;
        float acc = 0.0f;
        #pragma unroll
        for (int p = 0; p < 12; ++p) acc += Ss[q][p][hh] * Vs[p][hk];
        Os[q][hk] = acc;
    }
    __syncthreads();
    // projection in two 64-row halves of W_out, + residual, into Qs
    for (int half = 0; half < 2; ++half) {
        #pragma unroll
        for (int i = 0; i < 8; ++i) {
            int e = i * 256 + t;
            int row = e >> 5, c4 = e & 31;
            *reinterpret_cast<f32x4*>(&Ws[row][c4 * 4]) =
                *reinterpret_cast<const f32x4*>(&Wout[(size_t)(half * 64 + row) * DM + c4 * 4]);
        }
        __syncthreads();
        #pragma unroll
        for (int i = 0; i < 3; ++i) {
            int idx = i * 256 + t;
            int o = idx / 12, q = idx % 12;
            const f32x4* ov = reinterpret_cast<const f32x4*>(&Os[q][0]);
            const f32x4* wv = reinterpret_cast<const f32x4*>(&Ws[o][0]);
            float s = 0.0f;
            #pragma unroll
            for (int c = 0; c < 32; ++c) {
                f32x4 a = ov[c], bb = wv[c];
                s += a[0] * bb[0] + a[1] * bb[1] + a[2] * bb[2] + a[3] * bb[3];
            }
            int oo = half * 64 + o;
            size_t mrow = (size_t)(b * NP + q) * NN_ + n;
            Qs[q][oo] = s + xin[mrow * DM + oo];
        }
        __syncthreads();
    }
    // layernorm per row
    const int wv_ = t >> 6, l = t & 63;
    for (int rq = wv_; rq < 12; rq += 4) {
        float v0 = Qs[rq][l], v1 = Qs[rq][l + 64];
        float s = v0 + v1, ss = v0 * v0 + v1 * v1;
        #pragma unroll
        for (int msk = 1; msk < 64; msk <<= 1) {
            s += __shfl_xor(s, msk, 64);
            ss += __shfl_xor(ss, msk, 64);
        }
        float mu = s * (1.0f / 128.0f);
        float var = ss * (1.0f / 128.0f) - mu * mu;
        float rs = rsqrtf(var + 1e-5f);
        size_t mrow = (size_t)(b * NP + rq) * NN_ + n;
        out[mrow * DM + l]      = (v0 - mu) * rs * gamma[l] + beta[l];
        out[mrow * DM + l + 64] = (v1 - mu) * rs * gamma[l + 64] + beta[l + 64];
    }
}

// ---------------- launcher ----------------
extern "C" void kernel_launch(void* const* d_in, const int* in_sizes, int n_in,
                              void* d_out, int out_size, void* d_ws, size_t ws_size,
                              hipStream_t stream) {
    const float* xin   = (const float*)d_in[0];   // inputs   (B,P1,N,128)
    const float* Kenc  = (const float*)d_in[1];   // enc_K    (B,P,N,8,16)
    const float* Venc  = (const float*)d_in[2];   // enc_V
    const float* ct    = (const float*)d_in[3];   // c_targets
    const float* W1    = (const float*)d_in[4];   // (256,128)
    const float* b1    = (const float*)d_in[5];   // (256,)
    const float* W2    = (const float*)d_in[6];   // (16384,256)
    const float* b2    = (const float*)d_in[7];   // (16384,)
    const float* Wout  = (const float*)d_in[8];   // (128,128)
    const float* gamma = (const float*)d_in[9];
    const float* beta  = (const float*)d_in[10];
    float* out = (float*)d_out;

    char* ws = (char*)d_ws;
    unsigned short* W2b = (unsigned short*)(ws);                  //  8,388,608 B
    float* xT  = (float*)(ws + 8388608);                          //  5,111,808 B
    float* hb  = (float*)(ws + 13500416);                         // 10,223,616 B
    float* Qb  = (float*)(ws + 23724032);                         //  5,111,808 B
    float* Qp  = (float*)(ws + 28835840);                         // 40,894,464 B (8 splits)

    hipLaunchKernelGGL(k_cvt_w2,      dim3(2048), dim3(256), 0, stream, W2, W2b);
    hipLaunchKernelGGL(k_transpose_x, dim3(1248), dim3(256), 0, stream, xin, xT);
    hipLaunchKernelGGL(k_meta,        dim3(1242), dim3(256), 0, stream, ct, xin, W1, b1, b2, hb, Qb);
    hipLaunchKernelGGL(k_gemm,        dim3(624),  dim3(256), 0, stream, W2b, hb, xT, Qp);
    hipLaunchKernelGGL(k_attn,        dim3(828),  dim3(256), 0, stream, Qp, Qb, Kenc, Venc,
                       xin, Wout, gamma, beta, out);
}